// Round 1
// baseline (251.969 us; speedup 1.0000x reference)
//
#include <hip/hip_runtime.h>

// Problem constants (from reference)
#define N_SAMPLES 524288
#define N_FEATURES 64
#define N_GATES 64
#define N_OUTPUTS 8
#define BASE_COLS 66          // N_FEATURES + 2 (zero col, one col)
#define MAX_CONN 130          // BASE + N_GATES

// Tiling
#define SPB 128               // samples per block (== threads per block)
#define STR 129               // LDS row stride (SPB+1: makes transposed staging writes conflict-free)

// ---------------------------------------------------------------------------
// Kernel 1: top-2 connection indices per gate (uniform across samples).
// softmax is monotone, TEMPERATURE=1 -> top2 of probs == top2 of masked
// weights. Mask (col < BASE+i) implemented by scan bound. Strict '>' updates
// reproduce jax.lax.top_k's stable lowest-index-first tie-break.
// ---------------------------------------------------------------------------
__global__ void topk_prep_kernel(const float* __restrict__ gw, int2* __restrict__ gidx) {
    int i = threadIdx.x;            // one thread per gate, 64 threads
    if (i >= N_GATES) return;
    const float* w = gw + i * MAX_CONN;
    int avail = BASE_COLS + i;
    float v1 = -1e30f, v2 = -1e30f;
    int i1 = 0, i2 = 0;
    for (int j = 0; j < avail; ++j) {
        float x = w[j];
        if (x > v1) { v2 = v1; i2 = i1; v1 = x; i1 = j; }
        else if (x > v2) { v2 = x; i2 = j; }
    }
    gidx[i] = make_int2(i1, i2);
}

// ---------------------------------------------------------------------------
// Kernel 2: evaluate circuit. lane = sample, LDS row = buffer column.
// buf[c*STR + t]: reads have uniform c, consecutive t -> conflict-free.
// ---------------------------------------------------------------------------
__global__ __launch_bounds__(SPB) void circuit_kernel(
    const float* __restrict__ X,
    const int2*  __restrict__ gidx,
    const float* __restrict__ ow,     // [N_GATES][N_OUTPUTS]
    const float* __restrict__ scale,  // [N_OUTPUTS]
    float*       __restrict__ out)    // [N_SAMPLES][N_OUTPUTS]
{
    __shared__ float buf[MAX_CONN * STR];   // 130*129*4 = 67,080 B -> 2 blocks/CU

    const int t = threadIdx.x;
    const long long s0 = (long long)blockIdx.x * SPB;

    // ---- Stage X chunk (SPB x 64 floats, fully contiguous) into LDS, transposed.
    // Thread t, iter k loads float4 at chunk float-offset k*512 + 4t (coalesced:
    // 128 threads x 16B = 2KB contiguous per iter). col = off&63, sample = off>>6.
    // Bank of write = (c+j+s) % 32: covers all 32 residues exactly 2x per wave -> free.
    const float4* Xv = (const float4*)(X + s0 * N_FEATURES);
    #pragma unroll
    for (int k = 0; k < 16; ++k) {
        float4 v = Xv[k * SPB + t];
        int f = k * (SPB * 4) + t * 4;
        int c = f & 63;
        int s = f >> 6;
        buf[(c + 0) * STR + s] = v.x;
        buf[(c + 1) * STR + s] = v.y;
        buf[(c + 2) * STR + s] = v.z;
        buf[(c + 3) * STR + s] = v.w;
    }
    // Constant columns: 64 -> 0.0, 65 -> 1.0
    buf[64 * STR + t] = 0.0f;
    buf[65 * STR + t] = 1.0f;
    __syncthreads();

    float acc[N_OUTPUTS];
    #pragma unroll
    for (int o = 0; o < N_OUTPUTS; ++o) acc[o] = 0.0f;

    // ---- Sequential gates. Indices are wave-uniform (scalar loads).
    for (int i = 0; i < N_GATES; ++i) {
        int2 p = gidx[i];
        float a = buf[p.x * STR + t];
        float b = buf[p.y * STR + t];
        float g = 1.0f - a * b;
        buf[(BASE_COLS + i) * STR + t] = g;
        #pragma unroll
        for (int o = 0; o < N_OUTPUTS; ++o)
            acc[o] = fmaf(g, ow[i * N_OUTPUTS + o], acc[o]);
    }

    // ---- Epilogue: scale + coalesced store (2 x float4 per sample).
    float4 o0, o1;
    o0.x = acc[0] * scale[0]; o0.y = acc[1] * scale[1];
    o0.z = acc[2] * scale[2]; o0.w = acc[3] * scale[3];
    o1.x = acc[4] * scale[4]; o1.y = acc[5] * scale[5];
    o1.z = acc[6] * scale[6]; o1.w = acc[7] * scale[7];
    float4* outv = (float4*)(out + (s0 + t) * N_OUTPUTS);
    outv[0] = o0;
    outv[1] = o1;
}

extern "C" void kernel_launch(void* const* d_in, const int* in_sizes, int n_in,
                              void* d_out, int out_size, void* d_ws, size_t ws_size,
                              hipStream_t stream) {
    const float* X     = (const float*)d_in[0];  // [524288][64]
    const float* gw    = (const float*)d_in[1];  // [64][130]
    const float* ow    = (const float*)d_in[2];  // [64][8]
    const float* scale = (const float*)d_in[3];  // [8]
    float* out = (float*)d_out;                  // [524288][8]

    int2* gidx = (int2*)d_ws;                    // 64 * 8 B = 512 B scratch

    topk_prep_kernel<<<1, 64, 0, stream>>>(gw, gidx);

    int blocks = N_SAMPLES / SPB;                // 4096
    circuit_kernel<<<blocks, SPB, 0, stream>>>(X, gidx, ow, scale, out);
}

// Round 2
// 217.315 us; speedup vs baseline: 1.1595x; 1.1595x over previous
//
#include <hip/hip_runtime.h>
#include <hip/hip_fp16.h>

// Problem constants (from reference)
#define N_SAMPLES 524288
#define N_FEATURES 64
#define N_GATES 64
#define N_OUTPUTS 8
#define BASE_COLS 66          // N_FEATURES + 2 (zero col, one col)
#define MAX_CONN 130          // BASE + N_GATES

// Tiling: 128 threads/block, each thread owns ONE packed fp16x2 word = 2 samples.
#define TPB 256               // samples per block
#define NW 128                // words per row (= threads per block)
#define STR 129               // LDS row stride in words (NW+1)

// ---------------------------------------------------------------------------
// Kernel 1: top-2 connection indices per gate, one wave per gate.
// softmax monotone + TEMPERATURE=1 -> top2 of probs == top2 of masked weights.
// Tie-break: lower index wins (matches jax.lax.top_k stable order).
// ---------------------------------------------------------------------------
__device__ inline void top2_ins(float x, int j, float& v1, int& i1, float& v2, int& i2) {
    bool gt1 = (x > v1) || (x == v1 && j < i1);
    bool gt2 = (x > v2) || (x == v2 && j < i2);
    if (gt1) { v2 = v1; i2 = i1; v1 = x; i1 = j; }
    else if (gt2) { v2 = x; i2 = j; }
}

__global__ __launch_bounds__(64) void topk_prep_kernel(const float* __restrict__ gw,
                                                       int2* __restrict__ gidx) {
    const int i = blockIdx.x;        // gate id, 64 blocks
    const int l = threadIdx.x;       // lane 0..63
    const float* w = gw + i * MAX_CONN;
    const int avail = BASE_COLS + i; // columns [0, avail) are valid

    float v1 = -1e30f, v2 = -1e30f;
    int   i1 = 0x7fffffff, i2 = 0x7fffffff;
    // strips j = l, l+64, l+128 (avail <= 130) in increasing j
    for (int s = 0; s < 3; ++s) {
        int j = l + 64 * s;
        if (j < avail) top2_ins(w[j], j, v1, i1, v2, i2);
    }
    // butterfly merge across the 64-lane wave
    #pragma unroll
    for (int d = 1; d < 64; d <<= 1) {
        float ov1 = __shfl_xor(v1, d);
        int   oi1 = __shfl_xor(i1, d);
        float ov2 = __shfl_xor(v2, d);
        int   oi2 = __shfl_xor(i2, d);
        top2_ins(ov1, oi1, v1, i1, v2, i2);
        top2_ins(ov2, oi2, v1, i1, v2, i2);
    }
    if (l == 0) gidx[i] = make_int2(i1, i2);
}

// ---------------------------------------------------------------------------
// Kernel 2: evaluate circuit. LDS word [c][t] = half2(sample 2t, sample 2t+1).
// Reads in the gate loop have wave-uniform row c, lane-consecutive t -> conflict-free.
// ---------------------------------------------------------------------------
__global__ __launch_bounds__(NW) void circuit_kernel(
    const float* __restrict__ X,
    const int2*  __restrict__ gidx,
    const float* __restrict__ ow,     // [N_GATES][N_OUTPUTS]
    const float* __restrict__ scale,  // [N_OUTPUTS]
    float*       __restrict__ out)    // [N_SAMPLES][N_OUTPUTS]
{
    __shared__ __half2 buf[MAX_CONN * STR];   // 130*129*4 B = 67,080 B -> 2 blocks/CU

    const int t = threadIdx.x;                      // word owner, 0..127
    const long long s0 = (long long)blockIdx.x * TPB;

    // ---- Stage X chunk (TPB x 64 floats) into LDS, transposed + fp16-packed.
    // iter k, thread t: q = k*128+t in [0,2048): c4 = q&15 (float4 col), j = q>>4 (word).
    // Load rows 2j and 2j+1 at float4-column c4; pack pairs into half2 words.
    const float4* Xv = (const float4*)(X + s0 * N_FEATURES);
    #pragma unroll
    for (int k = 0; k < 16; ++k) {
        int q  = k * NW + t;
        int c4 = q & 15;
        int j  = q >> 4;
        float4 va = Xv[(2 * j)     * 16 + c4];
        float4 vb = Xv[(2 * j + 1) * 16 + c4];
        int c = 4 * c4;
        buf[(c + 0) * STR + j] = __halves2half2(__float2half(va.x), __float2half(vb.x));
        buf[(c + 1) * STR + j] = __halves2half2(__float2half(va.y), __float2half(vb.y));
        buf[(c + 2) * STR + j] = __halves2half2(__float2half(va.z), __float2half(vb.z));
        buf[(c + 3) * STR + j] = __halves2half2(__float2half(va.w), __float2half(vb.w));
    }
    // Constant columns: 64 -> 0.0, 65 -> 1.0
    buf[64 * STR + t] = __halves2half2(__float2half(0.0f), __float2half(0.0f));
    buf[65 * STR + t] = __halves2half2(__float2half(1.0f), __float2half(1.0f));
    __syncthreads();

    float acc0[N_OUTPUTS], acc1[N_OUTPUTS];
    #pragma unroll
    for (int o = 0; o < N_OUTPUTS; ++o) { acc0[o] = 0.0f; acc1[o] = 0.0f; }

    const __half2 one2 = __halves2half2(__float2half(1.0f), __float2half(1.0f));

    // ---- Sequential gates, fully unrolled (gidx/ow are wave-uniform scalar loads,
    // global address space -> hoistable past LDS ops).
    #pragma unroll
    for (int i = 0; i < N_GATES; ++i) {
        int2 p = gidx[i];
        __half2 a = buf[p.x * STR + t];
        __half2 b = buf[p.y * STR + t];
        __half2 g = __hfma2(__hneg2(a), b, one2);     // 1 - a*b (packed, 2 samples)
        buf[(BASE_COLS + i) * STR + t] = g;
        float g0 = __low2float(g);
        float g1 = __high2float(g);
        #pragma unroll
        for (int o = 0; o < N_OUTPUTS; ++o) {
            float w = ow[i * N_OUTPUTS + o];
            acc0[o] = fmaf(g0, w, acc0[o]);
            acc1[o] = fmaf(g1, w, acc1[o]);
        }
    }

    // ---- Epilogue: scale + coalesced store (4 x float4 per thread = 64 B/lane).
    float sc[N_OUTPUTS];
    #pragma unroll
    for (int o = 0; o < N_OUTPUTS; ++o) sc[o] = scale[o];

    float4* outv = (float4*)(out + (s0 + 2 * t) * N_OUTPUTS);
    outv[0] = make_float4(acc0[0] * sc[0], acc0[1] * sc[1], acc0[2] * sc[2], acc0[3] * sc[3]);
    outv[1] = make_float4(acc0[4] * sc[4], acc0[5] * sc[5], acc0[6] * sc[6], acc0[7] * sc[7]);
    outv[2] = make_float4(acc1[0] * sc[0], acc1[1] * sc[1], acc1[2] * sc[2], acc1[3] * sc[3]);
    outv[3] = make_float4(acc1[4] * sc[4], acc1[5] * sc[5], acc1[6] * sc[6], acc1[7] * sc[7]);
}

extern "C" void kernel_launch(void* const* d_in, const int* in_sizes, int n_in,
                              void* d_out, int out_size, void* d_ws, size_t ws_size,
                              hipStream_t stream) {
    const float* X     = (const float*)d_in[0];  // [524288][64]
    const float* gw    = (const float*)d_in[1];  // [64][130]
    const float* ow    = (const float*)d_in[2];  // [64][8]
    const float* scale = (const float*)d_in[3];  // [8]
    float* out = (float*)d_out;                  // [524288][8]

    int2* gidx = (int2*)d_ws;                    // 64 * 8 B scratch

    topk_prep_kernel<<<N_GATES, 64, 0, stream>>>(gw, gidx);

    int blocks = N_SAMPLES / TPB;                // 2048
    circuit_kernel<<<blocks, NW, 0, stream>>>(X, gidx, ow, scale, out);
}